// Round 1
// baseline (803.995 us; speedup 1.0000x reference)
//
#include <hip/hip_runtime.h>

#define N_NODES 100000
#define D 128
#define N_ADJ 6
#define NNZ 600000
#define N_HOPS 7
#define EDGES_TOTAL (N_ADJ * NNZ)

#define SCAN_CHUNK 1024
#define SCAN_BLOCKS ((N_NODES + SCAN_CHUNK - 1) / SCAN_CHUNK)  // 98

#define B_SHIFT 7
#define B_ROWS 128
#define NB ((N_NODES + B_ROWS - 1) / B_ROWS)   // 782 buckets
#define CHUNK 4096                              // edges per passA workgroup
#define EPT 16                                  // edges per thread (CHUNK/256)

typedef float f4_vec __attribute__((ext_vector_type(4)));

// Non-temporal 8B load of an int2 (streamed-once csr data; keep it out of L2
// so the gather working set keeps the capacity).
__device__ __forceinline__ int2 ldnt_i2(const int2* p) {
    unsigned long long u =
        __builtin_nontemporal_load((const unsigned long long*)p);
    return make_int2((int)(unsigned)u, (int)(u >> 32));
}

__device__ __forceinline__ void stnt_f4(float4* p, float4 v) {
    f4_vec t;
    t.x = v.x; t.y = v.y; t.z = v.z; t.w = v.w;
    __builtin_nontemporal_store(t, (f4_vec*)p);
}

// ---------------------------------------------------------------------------
// Phase 0: mix = softmax(linear_weight), 7 elements
// ---------------------------------------------------------------------------
__global__ void softmax_mix_kernel(const float* __restrict__ lw,
                                   float* __restrict__ mix) {
    if (threadIdx.x == 0) {
        float m = lw[0];
        for (int i = 1; i < N_HOPS; ++i) m = fmaxf(m, lw[i]);
        float e[N_HOPS];
        float s = 0.f;
        for (int i = 0; i < N_HOPS; ++i) { e[i] = __expf(lw[i] - m); s += e[i]; }
        float inv = 1.f / s;
        for (int i = 0; i < N_HOPS; ++i) mix[i] = e[i] * inv;
    }
}

// ---------------------------------------------------------------------------
// Row histogram (int atomics over 100k counters, low contention)
// ---------------------------------------------------------------------------
__global__ __launch_bounds__(256) void hist_kernel(
    const int* __restrict__ rows, int* __restrict__ counts) {
    int e = blockIdx.x * 256 + threadIdx.x;
    if (e < EDGES_TOTAL) atomicAdd(&counts[rows[e]], 1);
}

// ---------------------------------------------------------------------------
// Exclusive scan over row counts (3 kernels) -> offsets
// ---------------------------------------------------------------------------
__global__ __launch_bounds__(256) void scan_partial_kernel(
    const int* __restrict__ counts, int* __restrict__ blockSums) {
    __shared__ int lds[256];
    int base = blockIdx.x * SCAN_CHUNK;
    int t = threadIdx.x;
    int s = 0;
    #pragma unroll
    for (int k = 0; k < 4; ++k) {
        int i = base + t * 4 + k;
        s += (i < N_NODES) ? counts[i] : 0;
    }
    lds[t] = s;
    __syncthreads();
    for (int off = 128; off > 0; off >>= 1) {
        if (t < off) lds[t] += lds[t + off];
        __syncthreads();
    }
    if (t == 0) blockSums[blockIdx.x] = lds[0];
}

__global__ void scan_blocksums_kernel(int* __restrict__ blockSums) {
    if (threadIdx.x == 0) {
        int run = 0;
        for (int i = 0; i < SCAN_BLOCKS; ++i) {
            int c = blockSums[i];
            blockSums[i] = run;
            run += c;
        }
    }
}

__global__ __launch_bounds__(256) void scan_final_kernel(
    const int* __restrict__ counts, const int* __restrict__ blockSums,
    int* __restrict__ offsets) {
    __shared__ int lds[256];
    int base = blockIdx.x * SCAN_CHUNK;
    int t = threadIdx.x;
    int c[4];
    int s = 0;
    #pragma unroll
    for (int k = 0; k < 4; ++k) {
        int i = base + t * 4 + k;
        c[k] = (i < N_NODES) ? counts[i] : 0;
        s += c[k];
    }
    lds[t] = s;
    __syncthreads();
    for (int off = 1; off < 256; off <<= 1) {
        int u = 0;
        if (t >= off) u = lds[t - off];
        __syncthreads();
        if (t >= off) lds[t] += u;
        __syncthreads();
    }
    int texcl = lds[t] - s;
    int run = blockSums[blockIdx.x] + texcl;
    #pragma unroll
    for (int k = 0; k < 4; ++k) {
        int i = base + t * 4 + k;
        if (i < N_NODES) offsets[i] = run;
        run += c[k];
    }
    if (blockIdx.x == 0 && t == 0) offsets[N_NODES] = EDGES_TOTAL;
}

// ---------------------------------------------------------------------------
// bpos[b] = offsets[b*128]  (bucket write cursors for pass A)
// ---------------------------------------------------------------------------
__global__ void bpos_init_kernel(const int* __restrict__ offsets,
                                 int* __restrict__ bpos) {
    int b = blockIdx.x * 256 + threadIdx.x;
    if (b < NB) bpos[b] = offsets[b << B_SHIFT];
}

// ---------------------------------------------------------------------------
// Pass A: LDS-aggregated bucket scatter. Each WG stages a 4096-edge chunk in
// LDS grouped by bucket (row>>7), then flushes contiguous per-bucket runs to
// the bucketed tmp array. Payload: {rowLocal(7b)<<25 | col, premixed val}.
// Turns 223MB of partial-line random writes into ~45MB of short runs.
// ---------------------------------------------------------------------------
__global__ __launch_bounds__(256) void bucket_scatter_kernel(
    const int* __restrict__ rows, const int* __restrict__ cols,
    const float* __restrict__ vals, const float* __restrict__ mix,
    int* __restrict__ bpos, int2* __restrict__ tmp) {
    __shared__ int cnt[NB];
    __shared__ int off[NB];
    __shared__ int gbase[NB];
    __shared__ int scanbuf[256];
    __shared__ int2 stage[CHUNK];

    int base = blockIdx.x * CHUNK;
    int t = threadIdx.x;

    for (int i = t; i < NB; i += 256) cnt[i] = 0;
    __syncthreads();

    // Phase 1: count + capture slots
    int myRow[EPT];
    int mySlot[EPT];
    #pragma unroll
    for (int k = 0; k < EPT; ++k) {
        int e = base + k * 256 + t;
        if (e < EDGES_TOTAL) {
            int r = rows[e];
            myRow[k] = r;
            mySlot[k] = atomicAdd(&cnt[r >> B_SHIFT], 1);
        } else {
            myRow[k] = -1;
            mySlot[k] = 0;
        }
    }
    __syncthreads();

    // Exclusive scan of cnt[0..NB) (each thread owns 4 buckets)
    int i0 = t * 4;
    int c4[4];
    int s = 0;
    #pragma unroll
    for (int k = 0; k < 4; ++k) {
        int i = i0 + k;
        c4[k] = (i < NB) ? cnt[i] : 0;
        s += c4[k];
    }
    scanbuf[t] = s;
    __syncthreads();
    for (int o = 1; o < 256; o <<= 1) {
        int u = 0;
        if (t >= o) u = scanbuf[t - o];
        __syncthreads();
        if (t >= o) scanbuf[t] += u;
        __syncthreads();
    }
    int run = scanbuf[t] - s;
    #pragma unroll
    for (int k = 0; k < 4; ++k) {
        int i = i0 + k;
        if (i < NB) off[i] = run;
        run += c4[k];
    }
    // Reserve global ranges (one atomic per bucket per chunk)
    for (int i = t; i < NB; i += 256)
        gbase[i] = atomicAdd(&bpos[i], cnt[i]);
    __syncthreads();

    // Phase 2: place edges into LDS stage, bucket-grouped
    #pragma unroll
    for (int k = 0; k < EPT; ++k) {
        int e = base + k * 256 + t;
        int r = myRow[k];
        if (r >= 0) {
            int b = r >> B_SHIFT;
            int rl = r & (B_ROWS - 1);
            int a = e / NNZ;
            float v = vals[e] * mix[a + 1];
            int packed = (rl << 25) | cols[e];
            stage[off[b] + mySlot[k]] = make_int2(packed, __float_as_int(v));
        }
    }
    __syncthreads();

    // Phase 3: flush contiguous per-bucket runs to global
    for (int i = t; i < NB; i += 256) {
        int c = cnt[i];
        int g = gbase[i];
        int o = off[i];
        for (int j = 0; j < c; ++j) tmp[g + j] = stage[o + j];
    }
}

// ---------------------------------------------------------------------------
// Pass B: one WG per bucket. Reorder the bucket's edges into exact CSR order.
// Destination window ~37KB, single-CU -> full-line writebacks. Row cursors
// in LDS (no global atomics).
// ---------------------------------------------------------------------------
__global__ __launch_bounds__(256) void bucket_to_csr_kernel(
    const int* __restrict__ offsets, const int2* __restrict__ tmp,
    int2* __restrict__ csr) {
    __shared__ int lpos[B_ROWS];
    int b = blockIdx.x;
    int rbase = b << B_SHIFT;
    int t = threadIdx.x;
    if (t < B_ROWS) {
        int r = rbase + t;
        lpos[t] = offsets[(r < N_NODES) ? r : N_NODES];
    }
    __syncthreads();
    int start = offsets[rbase];
    int endr = rbase + B_ROWS;
    int end = offsets[(endr < N_NODES) ? endr : N_NODES];
    for (int j = start + t; j < end; j += 256) {
        int2 eo = tmp[j];
        int rl = ((unsigned)eo.x) >> 25;
        int col = eo.x & 0x01FFFFFF;
        int p = atomicAdd(&lpos[rl], 1);
        csr[p] = make_int2(col, eo.y);
    }
}

// ---------------------------------------------------------------------------
// Pull v2: half-wave (32 lanes x float4) per destination row, register acc.
// Changes vs v1 (theory: latency/MLP-bound at 3.7 TB/s, 59% of achievable):
//   - unroll 4: all 4 csr entry loads issued before any gather, then 4
//     independent 512B row-gathers in flight per half-wave (was ~2)
//   - 32-bit gather indexing: max byte offset 51.2MB < 2^31 -> SGPR base +
//     32-bit voffset, no 64-bit VALU addr chain per gather
//   - non-temporal csr loads + rep store: streamed-once data stops evicting
//     the gather-reuse working set from L2 (L2 currently gives 2.2x reuse)
// VGPR ~50, stays under the 64-VGPR occupancy step.
// ---------------------------------------------------------------------------
__global__ __launch_bounds__(256) void pull_kernel(
    const int* __restrict__ offsets, const int2* __restrict__ csr,
    const float4* __restrict__ in4, float4* __restrict__ rep4,
    const float* __restrict__ mix) {
    int row = blockIdx.x * 8 + (threadIdx.x >> 5);
    int l = threadIdx.x & 31;
    if (row >= N_NODES) return;
    int j = offsets[row];
    int end = offsets[row + 1];
    float m0 = mix[0];
    float4 x = in4[(row << 5) | l];
    float4 acc = make_float4(m0 * x.x, m0 * x.y, m0 * x.z, m0 * x.w);

    for (; j + 4 <= end; j += 4) {
        int2 e0 = ldnt_i2(csr + j + 0);
        int2 e1 = ldnt_i2(csr + j + 1);
        int2 e2 = ldnt_i2(csr + j + 2);
        int2 e3 = ldnt_i2(csr + j + 3);
        float4 y0 = in4[(e0.x << 5) | l];
        float4 y1 = in4[(e1.x << 5) | l];
        float4 y2 = in4[(e2.x << 5) | l];
        float4 y3 = in4[(e3.x << 5) | l];
        float v0 = __int_as_float(e0.y);
        float v1 = __int_as_float(e1.y);
        float v2 = __int_as_float(e2.y);
        float v3 = __int_as_float(e3.y);
        acc.x += v0 * y0.x; acc.y += v0 * y0.y; acc.z += v0 * y0.z; acc.w += v0 * y0.w;
        acc.x += v1 * y1.x; acc.y += v1 * y1.y; acc.z += v1 * y1.z; acc.w += v1 * y1.w;
        acc.x += v2 * y2.x; acc.y += v2 * y2.y; acc.z += v2 * y2.z; acc.w += v2 * y2.w;
        acc.x += v3 * y3.x; acc.y += v3 * y3.y; acc.z += v3 * y3.z; acc.w += v3 * y3.w;
    }
    if (j + 2 <= end) {
        int2 e0 = ldnt_i2(csr + j + 0);
        int2 e1 = ldnt_i2(csr + j + 1);
        float4 y0 = in4[(e0.x << 5) | l];
        float4 y1 = in4[(e1.x << 5) | l];
        float v0 = __int_as_float(e0.y);
        float v1 = __int_as_float(e1.y);
        acc.x += v0 * y0.x; acc.y += v0 * y0.y; acc.z += v0 * y0.z; acc.w += v0 * y0.w;
        acc.x += v1 * y1.x; acc.y += v1 * y1.y; acc.z += v1 * y1.z; acc.w += v1 * y1.w;
        j += 2;
    }
    if (j < end) {
        int2 e0 = ldnt_i2(csr + j);
        float v0 = __int_as_float(e0.y);
        float4 y0 = in4[(e0.x << 5) | l];
        acc.x += v0 * y0.x; acc.y += v0 * y0.y; acc.z += v0 * y0.z; acc.w += v0 * y0.w;
    }
    stnt_f4(&rep4[(row << 5) | l], acc);
}

// ---------------------------------------------------------------------------
// Fallback path (small ws): rep = mix[0]*input, then atomic push-scatter
// ---------------------------------------------------------------------------
__global__ __launch_bounds__(256) void rep_init_kernel(
    const float4* __restrict__ in4, float4* __restrict__ rep4,
    const float* __restrict__ mix) {
    int i = blockIdx.x * blockDim.x + threadIdx.x;
    if (i >= N_NODES * D / 4) return;
    float m0 = mix[0];
    float4 v = in4[i];
    v.x *= m0; v.y *= m0; v.z *= m0; v.w *= m0;
    rep4[i] = v;
}

__global__ __launch_bounds__(256) void scatter_kernel(
    const int* __restrict__ rows, const int* __restrict__ cols,
    const float* __restrict__ vals, const float4* __restrict__ in4,
    float* __restrict__ rep, const float* __restrict__ mix) {
    long long gid = (long long)blockIdx.x * blockDim.x + threadIdx.x;
    int e = (int)(gid >> 5);
    int l = (int)(gid & 31);
    if (e >= EDGES_TOTAL) return;
    int a = e / NNZ;
    int row = rows[e];
    int col = cols[e];
    float v = vals[e] * mix[a + 1];
    float4 x = in4[col * 32 + l];
    float* dst = rep + (long long)row * D + l * 4;
    atomicAdd(dst + 0, v * x.x);
    atomicAdd(dst + 1, v * x.y);
    atomicAdd(dst + 2, v * x.z);
    atomicAdd(dst + 3, v * x.w);
}

// ---------------------------------------------------------------------------
// out = rep @ W + bias. W (64KB f32) staged in LDS; 8 rows x 32 col-groups.
// ---------------------------------------------------------------------------
__global__ __launch_bounds__(256) void gemm_kernel(
    const float4* __restrict__ rep4, const float4* __restrict__ w4,
    const float4* __restrict__ bias4, float4* __restrict__ out4) {
    __shared__ float4 Wlds[D * (D / 4)];

    for (int idx = threadIdx.x; idx < D * (D / 4); idx += 256)
        Wlds[idx] = w4[idx];
    __syncthreads();

    int tc = threadIdx.x & 31;
    int rlocal = threadIdx.x >> 5;

    for (int base = blockIdx.x * 8; base < N_NODES; base += gridDim.x * 8) {
        int row = base + rlocal;
        if (row >= N_NODES) continue;
        float4 acc = make_float4(0.f, 0.f, 0.f, 0.f);
        const float4* reprow = rep4 + (long long)row * (D / 4);
        #pragma unroll 4
        for (int k4 = 0; k4 < D / 4; ++k4) {
            float4 a = reprow[k4];
            float4 w0 = Wlds[(k4 * 4 + 0) * 32 + tc];
            float4 w1 = Wlds[(k4 * 4 + 1) * 32 + tc];
            float4 w2 = Wlds[(k4 * 4 + 2) * 32 + tc];
            float4 w3 = Wlds[(k4 * 4 + 3) * 32 + tc];
            acc.x += a.x * w0.x; acc.y += a.x * w0.y; acc.z += a.x * w0.z; acc.w += a.x * w0.w;
            acc.x += a.y * w1.x; acc.y += a.y * w1.y; acc.z += a.y * w1.z; acc.w += a.y * w1.w;
            acc.x += a.z * w2.x; acc.y += a.z * w2.y; acc.z += a.z * w2.z; acc.w += a.z * w2.w;
            acc.x += a.w * w3.x; acc.y += a.w * w3.y; acc.z += a.w * w3.z; acc.w += a.w * w3.w;
        }
        float4 b = bias4[tc];
        acc.x += b.x; acc.y += b.y; acc.z += b.z; acc.w += b.w;
        out4[(long long)row * (D / 4) + tc] = acc;
    }
}

// ---------------------------------------------------------------------------
extern "C" void kernel_launch(void* const* d_in, const int* in_sizes, int n_in,
                              void* d_out, int out_size, void* d_ws, size_t ws_size,
                              hipStream_t stream) {
    const float* input         = (const float*)d_in[0];
    const int*   adj_rows      = (const int*)d_in[1];
    const int*   adj_cols      = (const int*)d_in[2];
    const float* adj_vals      = (const float*)d_in[3];
    const float* weight        = (const float*)d_in[4];
    const float* linear_weight = (const float*)d_in[5];
    const float* bias          = (const float*)d_in[6];

    float* out = (float*)d_out;                    // [N_NODES, D]
    float* rep = out + (size_t)N_NODES * D;        // [N_NODES, D]

    // tmp (bucketed edges) aliases the `out` region: out is only written by
    // the final gemm, after tmp's lifetime (passA write -> passB read) ends.
    int2* tmp = (int2*)out;                        // 28.8MB <= 51.2MB

    // workspace layout
    char* ws = (char*)d_ws;
    float* mix      = (float*)ws;                        ws += 32;
    int*   counts   = (int*)ws;                          ws += sizeof(int) * N_NODES;
    int*   offsets  = (int*)ws;                          ws += sizeof(int) * (N_NODES + 4);
    int*   blockSums= (int*)ws;                          ws += sizeof(int) * 128;
    int*   bpos     = (int*)ws;                          ws += sizeof(int) * (NB + 2);
    ws = (char*)(((uintptr_t)ws + 15) & ~(uintptr_t)15);
    int2*  csr      = (int2*)ws;                         ws += sizeof(int2) * EDGES_TOTAL;
    size_t needed = (size_t)(ws - (char*)d_ws);

    softmax_mix_kernel<<<1, 64, 0, stream>>>(linear_weight, mix);

    if (ws_size >= needed) {
        hipMemsetAsync(counts, 0, sizeof(int) * N_NODES, stream);
        {
            int blocks = (EDGES_TOTAL + 255) / 256;
            hist_kernel<<<blocks, 256, 0, stream>>>(adj_rows, counts);
        }
        scan_partial_kernel<<<SCAN_BLOCKS, 256, 0, stream>>>(counts, blockSums);
        scan_blocksums_kernel<<<1, 64, 0, stream>>>(blockSums);
        scan_final_kernel<<<SCAN_BLOCKS, 256, 0, stream>>>(counts, blockSums, offsets);
        bpos_init_kernel<<<(NB + 255) / 256, 256, 0, stream>>>(offsets, bpos);
        {
            int blocks = (EDGES_TOTAL + CHUNK - 1) / CHUNK;
            bucket_scatter_kernel<<<blocks, 256, 0, stream>>>(
                adj_rows, adj_cols, adj_vals, mix, bpos, tmp);
        }
        bucket_to_csr_kernel<<<NB, 256, 0, stream>>>(offsets, tmp, csr);
        {
            long long threads = (long long)N_NODES * 32;
            int blocks = (int)((threads + 255) / 256);
            pull_kernel<<<blocks, 256, 0, stream>>>(
                offsets, csr, (const float4*)input, (float4*)rep, mix);
        }
    } else {
        {
            int total = N_NODES * D / 4;
            int blocks = (total + 255) / 256;
            rep_init_kernel<<<blocks, 256, 0, stream>>>(
                (const float4*)input, (float4*)rep, mix);
        }
        {
            long long threads = (long long)EDGES_TOTAL * 32;
            int blocks = (int)((threads + 255) / 256);
            scatter_kernel<<<blocks, 256, 0, stream>>>(
                adj_rows, adj_cols, adj_vals, (const float4*)input, rep, mix);
        }
    }

    gemm_kernel<<<2048, 256, 0, stream>>>(
        (const float4*)rep, (const float4*)weight,
        (const float4*)bias, (float4*)out);
}

// Round 2
// 770.162 us; speedup vs baseline: 1.0439x; 1.0439x over previous
//
#include <hip/hip_runtime.h>

#define N_NODES 100000
#define D 128
#define N_ADJ 6
#define NNZ 600000
#define N_HOPS 7
#define EDGES_TOTAL (N_ADJ * NNZ)

#define SCAN_CHUNK 1024
#define SCAN_BLOCKS ((N_NODES + SCAN_CHUNK - 1) / SCAN_CHUNK)  // 98

#define B_SHIFT 7
#define B_ROWS 128
#define NB ((N_NODES + B_ROWS - 1) / B_ROWS)   // 782 buckets
#define CHUNK 4096                              // edges per passA workgroup
#define EPT 16                                  // edges per thread (CHUNK/256)

// ---------------------------------------------------------------------------
// Phase 0: mix = softmax(linear_weight), 7 elements
// ---------------------------------------------------------------------------
__global__ void softmax_mix_kernel(const float* __restrict__ lw,
                                   float* __restrict__ mix) {
    if (threadIdx.x == 0) {
        float m = lw[0];
        for (int i = 1; i < N_HOPS; ++i) m = fmaxf(m, lw[i]);
        float e[N_HOPS];
        float s = 0.f;
        for (int i = 0; i < N_HOPS; ++i) { e[i] = __expf(lw[i] - m); s += e[i]; }
        float inv = 1.f / s;
        for (int i = 0; i < N_HOPS; ++i) mix[i] = e[i] * inv;
    }
}

// ---------------------------------------------------------------------------
// Row histogram (int atomics over 100k counters, low contention)
// ---------------------------------------------------------------------------
__global__ __launch_bounds__(256) void hist_kernel(
    const int* __restrict__ rows, int* __restrict__ counts) {
    int e = blockIdx.x * 256 + threadIdx.x;
    if (e < EDGES_TOTAL) atomicAdd(&counts[rows[e]], 1);
}

// ---------------------------------------------------------------------------
// Exclusive scan over row counts (3 kernels) -> offsets
// ---------------------------------------------------------------------------
__global__ __launch_bounds__(256) void scan_partial_kernel(
    const int* __restrict__ counts, int* __restrict__ blockSums) {
    __shared__ int lds[256];
    int base = blockIdx.x * SCAN_CHUNK;
    int t = threadIdx.x;
    int s = 0;
    #pragma unroll
    for (int k = 0; k < 4; ++k) {
        int i = base + t * 4 + k;
        s += (i < N_NODES) ? counts[i] : 0;
    }
    lds[t] = s;
    __syncthreads();
    for (int off = 128; off > 0; off >>= 1) {
        if (t < off) lds[t] += lds[t + off];
        __syncthreads();
    }
    if (t == 0) blockSums[blockIdx.x] = lds[0];
}

__global__ void scan_blocksums_kernel(int* __restrict__ blockSums) {
    if (threadIdx.x == 0) {
        int run = 0;
        for (int i = 0; i < SCAN_BLOCKS; ++i) {
            int c = blockSums[i];
            blockSums[i] = run;
            run += c;
        }
    }
}

__global__ __launch_bounds__(256) void scan_final_kernel(
    const int* __restrict__ counts, const int* __restrict__ blockSums,
    int* __restrict__ offsets) {
    __shared__ int lds[256];
    int base = blockIdx.x * SCAN_CHUNK;
    int t = threadIdx.x;
    int c[4];
    int s = 0;
    #pragma unroll
    for (int k = 0; k < 4; ++k) {
        int i = base + t * 4 + k;
        c[k] = (i < N_NODES) ? counts[i] : 0;
        s += c[k];
    }
    lds[t] = s;
    __syncthreads();
    for (int off = 1; off < 256; off <<= 1) {
        int u = 0;
        if (t >= off) u = lds[t - off];
        __syncthreads();
        if (t >= off) lds[t] += u;
        __syncthreads();
    }
    int texcl = lds[t] - s;
    int run = blockSums[blockIdx.x] + texcl;
    #pragma unroll
    for (int k = 0; k < 4; ++k) {
        int i = base + t * 4 + k;
        if (i < N_NODES) offsets[i] = run;
        run += c[k];
    }
    if (blockIdx.x == 0 && t == 0) offsets[N_NODES] = EDGES_TOTAL;
}

// ---------------------------------------------------------------------------
// bpos[b] = offsets[b*128]  (bucket write cursors for pass A)
// ---------------------------------------------------------------------------
__global__ void bpos_init_kernel(const int* __restrict__ offsets,
                                 int* __restrict__ bpos) {
    int b = blockIdx.x * 256 + threadIdx.x;
    if (b < NB) bpos[b] = offsets[b << B_SHIFT];
}

// ---------------------------------------------------------------------------
// Pass A: LDS-aggregated bucket scatter. Each WG stages a 4096-edge chunk in
// LDS grouped by bucket (row>>7), then flushes to the bucketed tmp array.
// v2 flush: slot-major, binary search for owning bucket -> consecutive
// threads write consecutive global addresses (coalesced), instead of
// per-thread serial runs of ~5 scattered 8B stores.
// ---------------------------------------------------------------------------
__global__ __launch_bounds__(256) void bucket_scatter_kernel(
    const int* __restrict__ rows, const int* __restrict__ cols,
    const float* __restrict__ vals, const float* __restrict__ mix,
    int* __restrict__ bpos, int2* __restrict__ tmp) {
    __shared__ int cnt[NB];
    __shared__ int off[NB];
    __shared__ int gbase[NB];
    __shared__ int scanbuf[256];
    __shared__ int2 stage[CHUNK];

    int base = blockIdx.x * CHUNK;
    int t = threadIdx.x;

    for (int i = t; i < NB; i += 256) cnt[i] = 0;
    __syncthreads();

    // Phase 1: count + capture slots
    int myRow[EPT];
    int mySlot[EPT];
    #pragma unroll
    for (int k = 0; k < EPT; ++k) {
        int e = base + k * 256 + t;
        if (e < EDGES_TOTAL) {
            int r = rows[e];
            myRow[k] = r;
            mySlot[k] = atomicAdd(&cnt[r >> B_SHIFT], 1);
        } else {
            myRow[k] = -1;
            mySlot[k] = 0;
        }
    }
    __syncthreads();

    // Exclusive scan of cnt[0..NB) (each thread owns 4 buckets)
    int i0 = t * 4;
    int c4[4];
    int s = 0;
    #pragma unroll
    for (int k = 0; k < 4; ++k) {
        int i = i0 + k;
        c4[k] = (i < NB) ? cnt[i] : 0;
        s += c4[k];
    }
    scanbuf[t] = s;
    __syncthreads();
    for (int o = 1; o < 256; o <<= 1) {
        int u = 0;
        if (t >= o) u = scanbuf[t - o];
        __syncthreads();
        if (t >= o) scanbuf[t] += u;
        __syncthreads();
    }
    int run = scanbuf[t] - s;
    #pragma unroll
    for (int k = 0; k < 4; ++k) {
        int i = i0 + k;
        if (i < NB) off[i] = run;
        run += c4[k];
    }
    // Reserve global ranges (one atomic per bucket per chunk)
    for (int i = t; i < NB; i += 256)
        gbase[i] = atomicAdd(&bpos[i], cnt[i]);
    __syncthreads();

    // Phase 2: place edges into LDS stage, bucket-grouped
    #pragma unroll
    for (int k = 0; k < EPT; ++k) {
        int e = base + k * 256 + t;
        int r = myRow[k];
        if (r >= 0) {
            int b = r >> B_SHIFT;
            int rl = r & (B_ROWS - 1);
            int a = e / NNZ;
            float v = vals[e] * mix[a + 1];
            int packed = (rl << 25) | cols[e];
            stage[off[b] + mySlot[k]] = make_int2(packed, __float_as_int(v));
        }
    }
    __syncthreads();

    // Phase 3 (v2): slot-major coalesced flush. Thread handles stage slots
    // t, t+256, ... ; binary search off[] for the owning bucket.
    int totalE = EDGES_TOTAL - base;
    if (totalE > CHUNK) totalE = CHUNK;
    for (int s2 = t; s2 < totalE; s2 += 256) {
        int lo = 0, hi = NB - 1;
        while (lo < hi) {                 // largest b with off[b] <= s2
            int mid = (lo + hi + 1) >> 1;
            if (off[mid] <= s2) lo = mid; else hi = mid - 1;
        }
        tmp[gbase[lo] + (s2 - off[lo])] = stage[s2];
    }
}

// ---------------------------------------------------------------------------
// Pass B: one WG per bucket. Reorder the bucket's edges into exact CSR order.
// Destination window ~37KB, single-CU -> full-line writebacks. Row cursors
// in LDS (no global atomics).
// ---------------------------------------------------------------------------
__global__ __launch_bounds__(256) void bucket_to_csr_kernel(
    const int* __restrict__ offsets, const int2* __restrict__ tmp,
    int2* __restrict__ csr) {
    __shared__ int lpos[B_ROWS];
    int b = blockIdx.x;
    int rbase = b << B_SHIFT;
    int t = threadIdx.x;
    if (t < B_ROWS) {
        int r = rbase + t;
        lpos[t] = offsets[(r < N_NODES) ? r : N_NODES];
    }
    __syncthreads();
    int start = offsets[rbase];
    int endr = rbase + B_ROWS;
    int end = offsets[(endr < N_NODES) ? endr : N_NODES];
    for (int j = start + t; j < end; j += 256) {
        int2 eo = tmp[j];
        int rl = ((unsigned)eo.x) >> 25;
        int col = eo.x & 0x01FFFFFF;
        int p = atomicAdd(&lpos[rl], 1);
        csr[p] = make_int2(col, eo.y);
    }
}

// ---------------------------------------------------------------------------
// Pull v3: half-wave (32 lanes x float4) per destination row, register acc.
// Clean MLP test: unroll 4 (4 independent 512B row-gathers in flight per
// half-wave), 32-bit gather indexing, NO non-temporal hints (round-1 showed
// nt csr loads kill line reuse (+44MB FETCH) and nt rep store evicts the
// gemm input from L2).
// ---------------------------------------------------------------------------
__global__ __launch_bounds__(256) void pull_kernel(
    const int* __restrict__ offsets, const int2* __restrict__ csr,
    const float4* __restrict__ in4, float4* __restrict__ rep4,
    const float* __restrict__ mix) {
    int row = blockIdx.x * 8 + (threadIdx.x >> 5);
    int l = threadIdx.x & 31;
    if (row >= N_NODES) return;
    int j = offsets[row];
    int end = offsets[row + 1];
    float m0 = mix[0];
    float4 x = in4[(row << 5) | l];
    float4 acc = make_float4(m0 * x.x, m0 * x.y, m0 * x.z, m0 * x.w);

    for (; j + 4 <= end; j += 4) {
        int2 e0 = csr[j + 0];
        int2 e1 = csr[j + 1];
        int2 e2 = csr[j + 2];
        int2 e3 = csr[j + 3];
        float4 y0 = in4[(e0.x << 5) | l];
        float4 y1 = in4[(e1.x << 5) | l];
        float4 y2 = in4[(e2.x << 5) | l];
        float4 y3 = in4[(e3.x << 5) | l];
        float v0 = __int_as_float(e0.y);
        float v1 = __int_as_float(e1.y);
        float v2 = __int_as_float(e2.y);
        float v3 = __int_as_float(e3.y);
        acc.x += v0 * y0.x; acc.y += v0 * y0.y; acc.z += v0 * y0.z; acc.w += v0 * y0.w;
        acc.x += v1 * y1.x; acc.y += v1 * y1.y; acc.z += v1 * y1.z; acc.w += v1 * y1.w;
        acc.x += v2 * y2.x; acc.y += v2 * y2.y; acc.z += v2 * y2.z; acc.w += v2 * y2.w;
        acc.x += v3 * y3.x; acc.y += v3 * y3.y; acc.z += v3 * y3.z; acc.w += v3 * y3.w;
    }
    if (j + 2 <= end) {
        int2 e0 = csr[j + 0];
        int2 e1 = csr[j + 1];
        float4 y0 = in4[(e0.x << 5) | l];
        float4 y1 = in4[(e1.x << 5) | l];
        float v0 = __int_as_float(e0.y);
        float v1 = __int_as_float(e1.y);
        acc.x += v0 * y0.x; acc.y += v0 * y0.y; acc.z += v0 * y0.z; acc.w += v0 * y0.w;
        acc.x += v1 * y1.x; acc.y += v1 * y1.y; acc.z += v1 * y1.z; acc.w += v1 * y1.w;
        j += 2;
    }
    if (j < end) {
        int2 e0 = csr[j];
        float v0 = __int_as_float(e0.y);
        float4 y0 = in4[(e0.x << 5) | l];
        acc.x += v0 * y0.x; acc.y += v0 * y0.y; acc.z += v0 * y0.z; acc.w += v0 * y0.w;
    }
    rep4[(row << 5) | l] = acc;
}

// ---------------------------------------------------------------------------
// Fallback path (small ws): rep = mix[0]*input, then atomic push-scatter
// ---------------------------------------------------------------------------
__global__ __launch_bounds__(256) void rep_init_kernel(
    const float4* __restrict__ in4, float4* __restrict__ rep4,
    const float* __restrict__ mix) {
    int i = blockIdx.x * blockDim.x + threadIdx.x;
    if (i >= N_NODES * D / 4) return;
    float m0 = mix[0];
    float4 v = in4[i];
    v.x *= m0; v.y *= m0; v.z *= m0; v.w *= m0;
    rep4[i] = v;
}

__global__ __launch_bounds__(256) void scatter_kernel(
    const int* __restrict__ rows, const int* __restrict__ cols,
    const float* __restrict__ vals, const float4* __restrict__ in4,
    float* __restrict__ rep, const float* __restrict__ mix) {
    long long gid = (long long)blockIdx.x * blockDim.x + threadIdx.x;
    int e = (int)(gid >> 5);
    int l = (int)(gid & 31);
    if (e >= EDGES_TOTAL) return;
    int a = e / NNZ;
    int row = rows[e];
    int col = cols[e];
    float v = vals[e] * mix[a + 1];
    float4 x = in4[col * 32 + l];
    float* dst = rep + (long long)row * D + l * 4;
    atomicAdd(dst + 0, v * x.x);
    atomicAdd(dst + 1, v * x.y);
    atomicAdd(dst + 2, v * x.z);
    atomicAdd(dst + 3, v * x.w);
}

// ---------------------------------------------------------------------------
// out = rep @ W + bias. W (64KB f32) staged in LDS; 8 rows x 32 col-groups.
// ---------------------------------------------------------------------------
__global__ __launch_bounds__(256) void gemm_kernel(
    const float4* __restrict__ rep4, const float4* __restrict__ w4,
    const float4* __restrict__ bias4, float4* __restrict__ out4) {
    __shared__ float4 Wlds[D * (D / 4)];

    for (int idx = threadIdx.x; idx < D * (D / 4); idx += 256)
        Wlds[idx] = w4[idx];
    __syncthreads();

    int tc = threadIdx.x & 31;
    int rlocal = threadIdx.x >> 5;

    for (int base = blockIdx.x * 8; base < N_NODES; base += gridDim.x * 8) {
        int row = base + rlocal;
        if (row >= N_NODES) continue;
        float4 acc = make_float4(0.f, 0.f, 0.f, 0.f);
        const float4* reprow = rep4 + (long long)row * (D / 4);
        #pragma unroll 4
        for (int k4 = 0; k4 < D / 4; ++k4) {
            float4 a = reprow[k4];
            float4 w0 = Wlds[(k4 * 4 + 0) * 32 + tc];
            float4 w1 = Wlds[(k4 * 4 + 1) * 32 + tc];
            float4 w2 = Wlds[(k4 * 4 + 2) * 32 + tc];
            float4 w3 = Wlds[(k4 * 4 + 3) * 32 + tc];
            acc.x += a.x * w0.x; acc.y += a.x * w0.y; acc.z += a.x * w0.z; acc.w += a.x * w0.w;
            acc.x += a.y * w1.x; acc.y += a.y * w1.y; acc.z += a.y * w1.z; acc.w += a.y * w1.w;
            acc.x += a.z * w2.x; acc.y += a.z * w2.y; acc.z += a.z * w2.z; acc.w += a.z * w2.w;
            acc.x += a.w * w3.x; acc.y += a.w * w3.y; acc.z += a.w * w3.z; acc.w += a.w * w3.w;
        }
        float4 b = bias4[tc];
        acc.x += b.x; acc.y += b.y; acc.z += b.z; acc.w += b.w;
        out4[(long long)row * (D / 4) + tc] = acc;
    }
}

// ---------------------------------------------------------------------------
extern "C" void kernel_launch(void* const* d_in, const int* in_sizes, int n_in,
                              void* d_out, int out_size, void* d_ws, size_t ws_size,
                              hipStream_t stream) {
    const float* input         = (const float*)d_in[0];
    const int*   adj_rows      = (const int*)d_in[1];
    const int*   adj_cols      = (const int*)d_in[2];
    const float* adj_vals      = (const float*)d_in[3];
    const float* weight        = (const float*)d_in[4];
    const float* linear_weight = (const float*)d_in[5];
    const float* bias          = (const float*)d_in[6];

    float* out = (float*)d_out;                    // [N_NODES, D]
    float* rep = out + (size_t)N_NODES * D;        // [N_NODES, D]

    // tmp (bucketed edges) aliases the `out` region: out is only written by
    // the final gemm, after tmp's lifetime (passA write -> passB read) ends.
    int2* tmp = (int2*)out;                        // 28.8MB <= 51.2MB

    // workspace layout
    char* ws = (char*)d_ws;
    float* mix      = (float*)ws;                        ws += 32;
    int*   counts   = (int*)ws;                          ws += sizeof(int) * N_NODES;
    int*   offsets  = (int*)ws;                          ws += sizeof(int) * (N_NODES + 4);
    int*   blockSums= (int*)ws;                          ws += sizeof(int) * 128;
    int*   bpos     = (int*)ws;                          ws += sizeof(int) * (NB + 2);
    ws = (char*)(((uintptr_t)ws + 15) & ~(uintptr_t)15);
    int2*  csr      = (int2*)ws;                         ws += sizeof(int2) * EDGES_TOTAL;
    size_t needed = (size_t)(ws - (char*)d_ws);

    softmax_mix_kernel<<<1, 64, 0, stream>>>(linear_weight, mix);

    if (ws_size >= needed) {
        hipMemsetAsync(counts, 0, sizeof(int) * N_NODES, stream);
        {
            int blocks = (EDGES_TOTAL + 255) / 256;
            hist_kernel<<<blocks, 256, 0, stream>>>(adj_rows, counts);
        }
        scan_partial_kernel<<<SCAN_BLOCKS, 256, 0, stream>>>(counts, blockSums);
        scan_blocksums_kernel<<<1, 64, 0, stream>>>(blockSums);
        scan_final_kernel<<<SCAN_BLOCKS, 256, 0, stream>>>(counts, blockSums, offsets);
        bpos_init_kernel<<<(NB + 255) / 256, 256, 0, stream>>>(offsets, bpos);
        {
            int blocks = (EDGES_TOTAL + CHUNK - 1) / CHUNK;
            bucket_scatter_kernel<<<blocks, 256, 0, stream>>>(
                adj_rows, adj_cols, adj_vals, mix, bpos, tmp);
        }
        bucket_to_csr_kernel<<<NB, 256, 0, stream>>>(offsets, tmp, csr);
        {
            long long threads = (long long)N_NODES * 32;
            int blocks = (int)((threads + 255) / 256);
            pull_kernel<<<blocks, 256, 0, stream>>>(
                offsets, csr, (const float4*)input, (float4*)rep, mix);
        }
    } else {
        {
            int total = N_NODES * D / 4;
            int blocks = (total + 255) / 256;
            rep_init_kernel<<<blocks, 256, 0, stream>>>(
                (const float4*)input, (float4*)rep, mix);
        }
        {
            long long threads = (long long)EDGES_TOTAL * 32;
            int blocks = (int)((threads + 255) / 256);
            scatter_kernel<<<blocks, 256, 0, stream>>>(
                adj_rows, adj_cols, adj_vals, (const float4*)input, rep, mix);
        }
    }

    gemm_kernel<<<2048, 256, 0, stream>>>(
        (const float4*)rep, (const float4*)weight,
        (const float4*)bias, (float4*)out);
}

// Round 3
// 705.254 us; speedup vs baseline: 1.1400x; 1.0920x over previous
//
#include <hip/hip_runtime.h>
#include <hip/hip_fp16.h>

#define N_NODES 100000
#define D 128
#define N_ADJ 6
#define NNZ 600000
#define N_HOPS 7
#define EDGES_TOTAL (N_ADJ * NNZ)

#define SCAN_CHUNK 1024
#define SCAN_BLOCKS ((N_NODES + SCAN_CHUNK - 1) / SCAN_CHUNK)  // 98

#define B_SHIFT 7
#define B_ROWS 128
#define NB ((N_NODES + B_ROWS - 1) / B_ROWS)   // 782 buckets
#define CHUNK 4096                              // edges per passA workgroup
#define EPT 16                                  // edges per thread (CHUNK/256)

// ---------------------------------------------------------------------------
// Phase 0: mix = softmax(linear_weight), 7 elements
// ---------------------------------------------------------------------------
__global__ void softmax_mix_kernel(const float* __restrict__ lw,
                                   float* __restrict__ mix) {
    if (threadIdx.x == 0) {
        float m = lw[0];
        for (int i = 1; i < N_HOPS; ++i) m = fmaxf(m, lw[i]);
        float e[N_HOPS];
        float s = 0.f;
        for (int i = 0; i < N_HOPS; ++i) { e[i] = __expf(lw[i] - m); s += e[i]; }
        float inv = 1.f / s;
        for (int i = 0; i < N_HOPS; ++i) mix[i] = e[i] * inv;
    }
}

// ---------------------------------------------------------------------------
// input (f32) -> input16 (fp16). 8 floats per thread, 16B stores.
// fp16 u=2^-11 on N(0,1) data: propagated error to out ~1e-3, an order below
// the fp32 path's existing 0.0078 absmax. Halves the gather working set.
// ---------------------------------------------------------------------------
__global__ __launch_bounds__(256) void conv16_kernel(
    const float4* __restrict__ in4, uint4* __restrict__ o16) {
    int i = blockIdx.x * 256 + threadIdx.x;
    if (i >= N_NODES * D / 8) return;
    float4 a = in4[2 * i];
    float4 b = in4[2 * i + 1];
    __half2 h0 = __floats2half2_rn(a.x, a.y);
    __half2 h1 = __floats2half2_rn(a.z, a.w);
    __half2 h2 = __floats2half2_rn(b.x, b.y);
    __half2 h3 = __floats2half2_rn(b.z, b.w);
    uint4 u;
    u.x = *reinterpret_cast<unsigned int*>(&h0);
    u.y = *reinterpret_cast<unsigned int*>(&h1);
    u.z = *reinterpret_cast<unsigned int*>(&h2);
    u.w = *reinterpret_cast<unsigned int*>(&h3);
    o16[i] = u;
}

// ---------------------------------------------------------------------------
// Row histogram (int atomics over 100k counters, low contention)
// ---------------------------------------------------------------------------
__global__ __launch_bounds__(256) void hist_kernel(
    const int* __restrict__ rows, int* __restrict__ counts) {
    int e = blockIdx.x * 256 + threadIdx.x;
    if (e < EDGES_TOTAL) atomicAdd(&counts[rows[e]], 1);
}

// ---------------------------------------------------------------------------
// Exclusive scan over row counts (3 kernels) -> offsets
// ---------------------------------------------------------------------------
__global__ __launch_bounds__(256) void scan_partial_kernel(
    const int* __restrict__ counts, int* __restrict__ blockSums) {
    __shared__ int lds[256];
    int base = blockIdx.x * SCAN_CHUNK;
    int t = threadIdx.x;
    int s = 0;
    #pragma unroll
    for (int k = 0; k < 4; ++k) {
        int i = base + t * 4 + k;
        s += (i < N_NODES) ? counts[i] : 0;
    }
    lds[t] = s;
    __syncthreads();
    for (int off = 128; off > 0; off >>= 1) {
        if (t < off) lds[t] += lds[t + off];
        __syncthreads();
    }
    if (t == 0) blockSums[blockIdx.x] = lds[0];
}

__global__ void scan_blocksums_kernel(int* __restrict__ blockSums) {
    if (threadIdx.x == 0) {
        int run = 0;
        for (int i = 0; i < SCAN_BLOCKS; ++i) {
            int c = blockSums[i];
            blockSums[i] = run;
            run += c;
        }
    }
}

__global__ __launch_bounds__(256) void scan_final_kernel(
    const int* __restrict__ counts, const int* __restrict__ blockSums,
    int* __restrict__ offsets) {
    __shared__ int lds[256];
    int base = blockIdx.x * SCAN_CHUNK;
    int t = threadIdx.x;
    int c[4];
    int s = 0;
    #pragma unroll
    for (int k = 0; k < 4; ++k) {
        int i = base + t * 4 + k;
        c[k] = (i < N_NODES) ? counts[i] : 0;
        s += c[k];
    }
    lds[t] = s;
    __syncthreads();
    for (int off = 1; off < 256; off <<= 1) {
        int u = 0;
        if (t >= off) u = lds[t - off];
        __syncthreads();
        if (t >= off) lds[t] += u;
        __syncthreads();
    }
    int texcl = lds[t] - s;
    int run = blockSums[blockIdx.x] + texcl;
    #pragma unroll
    for (int k = 0; k < 4; ++k) {
        int i = base + t * 4 + k;
        if (i < N_NODES) offsets[i] = run;
        run += c[k];
    }
    if (blockIdx.x == 0 && t == 0) offsets[N_NODES] = EDGES_TOTAL;
}

// ---------------------------------------------------------------------------
// bpos[b] = offsets[b*128]  (bucket write cursors for pass A)
// ---------------------------------------------------------------------------
__global__ void bpos_init_kernel(const int* __restrict__ offsets,
                                 int* __restrict__ bpos) {
    int b = blockIdx.x * 256 + threadIdx.x;
    if (b < NB) bpos[b] = offsets[b << B_SHIFT];
}

// ---------------------------------------------------------------------------
// Pass A: LDS-aggregated bucket scatter. Each WG stages a 4096-edge chunk in
// LDS grouped by bucket (row>>7), then flushes contiguous per-bucket runs to
// the bucketed tmp array. Payload: {rowLocal(7b)<<25 | col, premixed val}.
// (round-0 flush restored: per-bucket serial runs measured best)
// ---------------------------------------------------------------------------
__global__ __launch_bounds__(256) void bucket_scatter_kernel(
    const int* __restrict__ rows, const int* __restrict__ cols,
    const float* __restrict__ vals, const float* __restrict__ mix,
    int* __restrict__ bpos, int2* __restrict__ tmp) {
    __shared__ int cnt[NB];
    __shared__ int off[NB];
    __shared__ int gbase[NB];
    __shared__ int scanbuf[256];
    __shared__ int2 stage[CHUNK];

    int base = blockIdx.x * CHUNK;
    int t = threadIdx.x;

    for (int i = t; i < NB; i += 256) cnt[i] = 0;
    __syncthreads();

    // Phase 1: count + capture slots
    int myRow[EPT];
    int mySlot[EPT];
    #pragma unroll
    for (int k = 0; k < EPT; ++k) {
        int e = base + k * 256 + t;
        if (e < EDGES_TOTAL) {
            int r = rows[e];
            myRow[k] = r;
            mySlot[k] = atomicAdd(&cnt[r >> B_SHIFT], 1);
        } else {
            myRow[k] = -1;
            mySlot[k] = 0;
        }
    }
    __syncthreads();

    // Exclusive scan of cnt[0..NB) (each thread owns 4 buckets)
    int i0 = t * 4;
    int c4[4];
    int s = 0;
    #pragma unroll
    for (int k = 0; k < 4; ++k) {
        int i = i0 + k;
        c4[k] = (i < NB) ? cnt[i] : 0;
        s += c4[k];
    }
    scanbuf[t] = s;
    __syncthreads();
    for (int o = 1; o < 256; o <<= 1) {
        int u = 0;
        if (t >= o) u = scanbuf[t - o];
        __syncthreads();
        if (t >= o) scanbuf[t] += u;
        __syncthreads();
    }
    int run = scanbuf[t] - s;
    #pragma unroll
    for (int k = 0; k < 4; ++k) {
        int i = i0 + k;
        if (i < NB) off[i] = run;
        run += c4[k];
    }
    // Reserve global ranges (one atomic per bucket per chunk)
    for (int i = t; i < NB; i += 256)
        gbase[i] = atomicAdd(&bpos[i], cnt[i]);
    __syncthreads();

    // Phase 2: place edges into LDS stage, bucket-grouped
    #pragma unroll
    for (int k = 0; k < EPT; ++k) {
        int e = base + k * 256 + t;
        int r = myRow[k];
        if (r >= 0) {
            int b = r >> B_SHIFT;
            int rl = r & (B_ROWS - 1);
            int a = e / NNZ;
            float v = vals[e] * mix[a + 1];
            int packed = (rl << 25) | cols[e];
            stage[off[b] + mySlot[k]] = make_int2(packed, __float_as_int(v));
        }
    }
    __syncthreads();

    // Phase 3: flush contiguous per-bucket runs to global
    for (int i = t; i < NB; i += 256) {
        int c = cnt[i];
        int g = gbase[i];
        int o = off[i];
        for (int j = 0; j < c; ++j) tmp[g + j] = stage[o + j];
    }
}

// ---------------------------------------------------------------------------
// Pass B: one WG per bucket. Reorder the bucket's edges into exact CSR order.
// ---------------------------------------------------------------------------
__global__ __launch_bounds__(256) void bucket_to_csr_kernel(
    const int* __restrict__ offsets, const int2* __restrict__ tmp,
    int2* __restrict__ csr) {
    __shared__ int lpos[B_ROWS];
    int b = blockIdx.x;
    int rbase = b << B_SHIFT;
    int t = threadIdx.x;
    if (t < B_ROWS) {
        int r = rbase + t;
        lpos[t] = offsets[(r < N_NODES) ? r : N_NODES];
    }
    __syncthreads();
    int start = offsets[rbase];
    int endr = rbase + B_ROWS;
    int end = offsets[(endr < N_NODES) ? endr : N_NODES];
    for (int j = start + t; j < end; j += 256) {
        int2 eo = tmp[j];
        int rl = ((unsigned)eo.x) >> 25;
        int col = eo.x & 0x01FFFFFF;
        int p = atomicAdd(&lpos[rl], 1);
        csr[p] = make_int2(col, eo.y);
    }
}

// ---------------------------------------------------------------------------
// Pull v4 (fp16): 16 lanes x uint4(=8 halves) per destination row.
// vs f32 pull: gather bytes halve (256B rows) AND one wave instruction now
// serves 4 rows (64 lanes x 16B = 4 x 256B), halving miss-request count too.
// Accumulate in fp32.
// ---------------------------------------------------------------------------
__device__ __forceinline__ void h8_fma(uint4 u, float v, float* a) {
    __half2* hp = reinterpret_cast<__half2*>(&u);
    #pragma unroll
    for (int k = 0; k < 4; ++k) {
        float2 f = __half22float2(hp[k]);
        a[2 * k]     += v * f.x;
        a[2 * k + 1] += v * f.y;
    }
}

__global__ __launch_bounds__(256) void pull16_kernel(
    const int* __restrict__ offsets, const int2* __restrict__ csr,
    const uint4* __restrict__ in16, float4* __restrict__ rep4,
    const float* __restrict__ mix) {
    int row = blockIdx.x * 16 + (threadIdx.x >> 4);
    int l = threadIdx.x & 15;
    if (row >= N_NODES) return;
    int j = offsets[row];
    int end = offsets[row + 1];
    float m0 = mix[0];
    float a[8];
    {
        uint4 xs = in16[(row << 4) | l];
        __half2* hp = reinterpret_cast<__half2*>(&xs);
        #pragma unroll
        for (int k = 0; k < 4; ++k) {
            float2 f = __half22float2(hp[k]);
            a[2 * k]     = m0 * f.x;
            a[2 * k + 1] = m0 * f.y;
        }
    }
    for (; j + 4 <= end; j += 4) {
        int2 e0 = csr[j + 0];
        int2 e1 = csr[j + 1];
        int2 e2 = csr[j + 2];
        int2 e3 = csr[j + 3];
        uint4 y0 = in16[(e0.x << 4) | l];
        uint4 y1 = in16[(e1.x << 4) | l];
        uint4 y2 = in16[(e2.x << 4) | l];
        uint4 y3 = in16[(e3.x << 4) | l];
        h8_fma(y0, __int_as_float(e0.y), a);
        h8_fma(y1, __int_as_float(e1.y), a);
        h8_fma(y2, __int_as_float(e2.y), a);
        h8_fma(y3, __int_as_float(e3.y), a);
    }
    for (; j < end; ++j) {
        int2 e = csr[j];
        uint4 y = in16[(e.x << 4) | l];
        h8_fma(y, __int_as_float(e.y), a);
    }
    int o = (row << 5) | (l << 1);
    rep4[o]     = make_float4(a[0], a[1], a[2], a[3]);
    rep4[o + 1] = make_float4(a[4], a[5], a[6], a[7]);
}

// ---------------------------------------------------------------------------
// Pull (f32, middle path when ws can't hold input16): round-0 version.
// ---------------------------------------------------------------------------
__global__ __launch_bounds__(256) void pull_kernel(
    const int* __restrict__ offsets, const int2* __restrict__ csr,
    const float4* __restrict__ in4, float4* __restrict__ rep4,
    const float* __restrict__ mix) {
    int row = blockIdx.x * 8 + (threadIdx.x >> 5);
    int l = threadIdx.x & 31;
    if (row >= N_NODES) return;
    int j = offsets[row];
    int end = offsets[row + 1];
    float m0 = mix[0];
    float4 x = in4[(row << 5) | l];
    float4 acc = make_float4(m0 * x.x, m0 * x.y, m0 * x.z, m0 * x.w);
    for (; j + 1 < end; j += 2) {
        int2 e0 = csr[j];
        int2 e1 = csr[j + 1];
        float v0 = __int_as_float(e0.y);
        float v1 = __int_as_float(e1.y);
        float4 y0 = in4[(e0.x << 5) | l];
        float4 y1 = in4[(e1.x << 5) | l];
        acc.x += v0 * y0.x; acc.y += v0 * y0.y; acc.z += v0 * y0.z; acc.w += v0 * y0.w;
        acc.x += v1 * y1.x; acc.y += v1 * y1.y; acc.z += v1 * y1.z; acc.w += v1 * y1.w;
    }
    if (j < end) {
        int2 e0 = csr[j];
        float v0 = __int_as_float(e0.y);
        float4 y0 = in4[(e0.x << 5) | l];
        acc.x += v0 * y0.x; acc.y += v0 * y0.y; acc.z += v0 * y0.z; acc.w += v0 * y0.w;
    }
    rep4[(row << 5) | l] = acc;
}

// ---------------------------------------------------------------------------
// Fallback path (small ws): rep = mix[0]*input, then atomic push-scatter
// ---------------------------------------------------------------------------
__global__ __launch_bounds__(256) void rep_init_kernel(
    const float4* __restrict__ in4, float4* __restrict__ rep4,
    const float* __restrict__ mix) {
    int i = blockIdx.x * blockDim.x + threadIdx.x;
    if (i >= N_NODES * D / 4) return;
    float m0 = mix[0];
    float4 v = in4[i];
    v.x *= m0; v.y *= m0; v.z *= m0; v.w *= m0;
    rep4[i] = v;
}

__global__ __launch_bounds__(256) void scatter_kernel(
    const int* __restrict__ rows, const int* __restrict__ cols,
    const float* __restrict__ vals, const float4* __restrict__ in4,
    float* __restrict__ rep, const float* __restrict__ mix) {
    long long gid = (long long)blockIdx.x * blockDim.x + threadIdx.x;
    int e = (int)(gid >> 5);
    int l = (int)(gid & 31);
    if (e >= EDGES_TOTAL) return;
    int a = e / NNZ;
    int row = rows[e];
    int col = cols[e];
    float v = vals[e] * mix[a + 1];
    float4 x = in4[col * 32 + l];
    float* dst = rep + (long long)row * D + l * 4;
    atomicAdd(dst + 0, v * x.x);
    atomicAdd(dst + 1, v * x.y);
    atomicAdd(dst + 2, v * x.z);
    atomicAdd(dst + 3, v * x.w);
}

// ---------------------------------------------------------------------------
// out = rep @ W + bias. W (64KB f32) staged in LDS; 8 rows x 32 col-groups.
// ---------------------------------------------------------------------------
__global__ __launch_bounds__(256) void gemm_kernel(
    const float4* __restrict__ rep4, const float4* __restrict__ w4,
    const float4* __restrict__ bias4, float4* __restrict__ out4) {
    __shared__ float4 Wlds[D * (D / 4)];

    for (int idx = threadIdx.x; idx < D * (D / 4); idx += 256)
        Wlds[idx] = w4[idx];
    __syncthreads();

    int tc = threadIdx.x & 31;
    int rlocal = threadIdx.x >> 5;

    for (int base = blockIdx.x * 8; base < N_NODES; base += gridDim.x * 8) {
        int row = base + rlocal;
        if (row >= N_NODES) continue;
        float4 acc = make_float4(0.f, 0.f, 0.f, 0.f);
        const float4* reprow = rep4 + (long long)row * (D / 4);
        #pragma unroll 4
        for (int k4 = 0; k4 < D / 4; ++k4) {
            float4 a = reprow[k4];
            float4 w0 = Wlds[(k4 * 4 + 0) * 32 + tc];
            float4 w1 = Wlds[(k4 * 4 + 1) * 32 + tc];
            float4 w2 = Wlds[(k4 * 4 + 2) * 32 + tc];
            float4 w3 = Wlds[(k4 * 4 + 3) * 32 + tc];
            acc.x += a.x * w0.x; acc.y += a.x * w0.y; acc.z += a.x * w0.z; acc.w += a.x * w0.w;
            acc.x += a.y * w1.x; acc.y += a.y * w1.y; acc.z += a.y * w1.z; acc.w += a.y * w1.w;
            acc.x += a.z * w2.x; acc.y += a.z * w2.y; acc.z += a.z * w2.z; acc.w += a.z * w2.w;
            acc.x += a.w * w3.x; acc.y += a.w * w3.y; acc.z += a.w * w3.z; acc.w += a.w * w3.w;
        }
        float4 b = bias4[tc];
        acc.x += b.x; acc.y += b.y; acc.z += b.z; acc.w += b.w;
        out4[(long long)row * (D / 4) + tc] = acc;
    }
}

// ---------------------------------------------------------------------------
extern "C" void kernel_launch(void* const* d_in, const int* in_sizes, int n_in,
                              void* d_out, int out_size, void* d_ws, size_t ws_size,
                              hipStream_t stream) {
    const float* input         = (const float*)d_in[0];
    const int*   adj_rows      = (const int*)d_in[1];
    const int*   adj_cols      = (const int*)d_in[2];
    const float* adj_vals      = (const float*)d_in[3];
    const float* weight        = (const float*)d_in[4];
    const float* linear_weight = (const float*)d_in[5];
    const float* bias          = (const float*)d_in[6];

    float* out = (float*)d_out;                    // [N_NODES, D]
    float* rep = out + (size_t)N_NODES * D;        // [N_NODES, D]

    // tmp (bucketed edges) aliases the `out` region: out is only written by
    // the final gemm, after tmp's lifetime (passA write -> passB read) ends.
    int2* tmp = (int2*)out;                        // 28.8MB <= 51.2MB

    // workspace layout
    char* ws = (char*)d_ws;
    float* mix      = (float*)ws;                        ws += 32;
    int*   counts   = (int*)ws;                          ws += sizeof(int) * N_NODES;
    int*   offsets  = (int*)ws;                          ws += sizeof(int) * (N_NODES + 4);
    int*   blockSums= (int*)ws;                          ws += sizeof(int) * 128;
    int*   bpos     = (int*)ws;                          ws += sizeof(int) * (NB + 2);
    ws = (char*)(((uintptr_t)ws + 15) & ~(uintptr_t)15);
    int2*  csr      = (int2*)ws;                         ws += sizeof(int2) * EDGES_TOTAL;
    size_t needed1 = (size_t)(ws - (char*)d_ws);
    ws = (char*)(((uintptr_t)ws + 15) & ~(uintptr_t)15);
    uint4* input16  = (uint4*)ws;                        ws += sizeof(unsigned short) * (size_t)N_NODES * D;
    size_t needed2 = (size_t)(ws - (char*)d_ws);

    softmax_mix_kernel<<<1, 64, 0, stream>>>(linear_weight, mix);

    if (ws_size >= needed1) {
        bool fp16path = (ws_size >= needed2);

        hipMemsetAsync(counts, 0, sizeof(int) * N_NODES, stream);
        if (fp16path) {
            int total = N_NODES * D / 8;
            conv16_kernel<<<(total + 255) / 256, 256, 0, stream>>>(
                (const float4*)input, input16);
        }
        {
            int blocks = (EDGES_TOTAL + 255) / 256;
            hist_kernel<<<blocks, 256, 0, stream>>>(adj_rows, counts);
        }
        scan_partial_kernel<<<SCAN_BLOCKS, 256, 0, stream>>>(counts, blockSums);
        scan_blocksums_kernel<<<1, 64, 0, stream>>>(blockSums);
        scan_final_kernel<<<SCAN_BLOCKS, 256, 0, stream>>>(counts, blockSums, offsets);
        bpos_init_kernel<<<(NB + 255) / 256, 256, 0, stream>>>(offsets, bpos);
        {
            int blocks = (EDGES_TOTAL + CHUNK - 1) / CHUNK;
            bucket_scatter_kernel<<<blocks, 256, 0, stream>>>(
                adj_rows, adj_cols, adj_vals, mix, bpos, tmp);
        }
        bucket_to_csr_kernel<<<NB, 256, 0, stream>>>(offsets, tmp, csr);
        if (fp16path) {
            int blocks = (N_NODES * 16 + 255) / 256;
            pull16_kernel<<<blocks, 256, 0, stream>>>(
                offsets, csr, input16, (float4*)rep, mix);
        } else {
            long long threads = (long long)N_NODES * 32;
            int blocks = (int)((threads + 255) / 256);
            pull_kernel<<<blocks, 256, 0, stream>>>(
                offsets, csr, (const float4*)input, (float4*)rep, mix);
        }
    } else {
        {
            int total = N_NODES * D / 4;
            int blocks = (total + 255) / 256;
            rep_init_kernel<<<blocks, 256, 0, stream>>>(
                (const float4*)input, (float4*)rep, mix);
        }
        {
            long long threads = (long long)EDGES_TOTAL * 32;
            int blocks = (int)((threads + 255) / 256);
            scatter_kernel<<<blocks, 256, 0, stream>>>(
                adj_rows, adj_cols, adj_vals, (const float4*)input, rep, mix);
        }
    }

    gemm_kernel<<<2048, 256, 0, stream>>>(
        (const float4*)rep, (const float4*)weight,
        (const float4*)bias, (float4*)out);
}

// Round 4
// 681.299 us; speedup vs baseline: 1.1801x; 1.0352x over previous
//
#include <hip/hip_runtime.h>
#include <hip/hip_fp16.h>

#define N_NODES 100000
#define D 128
#define N_ADJ 6
#define NNZ 600000
#define N_HOPS 7
#define EDGES_TOTAL (N_ADJ * NNZ)

#define SCAN_CHUNK 1024
#define SCAN_BLOCKS ((N_NODES + SCAN_CHUNK - 1) / SCAN_CHUNK)  // 98

#define B_SHIFT 7
#define B_ROWS 128
#define NB ((N_NODES + B_ROWS - 1) / B_ROWS)   // 782 buckets
#define CHUNK 4096                              // edges per passA workgroup
#define EPT 16                                  // edges per thread (CHUNK/256)

// ---------------------------------------------------------------------------
// Phase 0: mix = softmax(linear_weight), 7 elements
// ---------------------------------------------------------------------------
__global__ void softmax_mix_kernel(const float* __restrict__ lw,
                                   float* __restrict__ mix) {
    if (threadIdx.x == 0) {
        float m = lw[0];
        for (int i = 1; i < N_HOPS; ++i) m = fmaxf(m, lw[i]);
        float e[N_HOPS];
        float s = 0.f;
        for (int i = 0; i < N_HOPS; ++i) { e[i] = __expf(lw[i] - m); s += e[i]; }
        float inv = 1.f / s;
        for (int i = 0; i < N_HOPS; ++i) mix[i] = e[i] * inv;
    }
}

// ---------------------------------------------------------------------------
// input (f32) -> input16 (fp16). 8 floats per thread, 16B stores.
// ---------------------------------------------------------------------------
__global__ __launch_bounds__(256) void conv16_kernel(
    const float4* __restrict__ in4, uint4* __restrict__ o16) {
    int i = blockIdx.x * 256 + threadIdx.x;
    if (i >= N_NODES * D / 8) return;
    float4 a = in4[2 * i];
    float4 b = in4[2 * i + 1];
    __half2 h0 = __floats2half2_rn(a.x, a.y);
    __half2 h1 = __floats2half2_rn(a.z, a.w);
    __half2 h2 = __floats2half2_rn(b.x, b.y);
    __half2 h3 = __floats2half2_rn(b.z, b.w);
    uint4 u;
    u.x = *reinterpret_cast<unsigned int*>(&h0);
    u.y = *reinterpret_cast<unsigned int*>(&h1);
    u.z = *reinterpret_cast<unsigned int*>(&h2);
    u.w = *reinterpret_cast<unsigned int*>(&h3);
    o16[i] = u;
}

// ---------------------------------------------------------------------------
// Row histogram (int atomics over 100k counters, low contention)
// ---------------------------------------------------------------------------
__global__ __launch_bounds__(256) void hist_kernel(
    const int* __restrict__ rows, int* __restrict__ counts) {
    int e = blockIdx.x * 256 + threadIdx.x;
    if (e < EDGES_TOTAL) atomicAdd(&counts[rows[e]], 1);
}

// ---------------------------------------------------------------------------
// Exclusive scan over row counts (3 kernels) -> offsets
// ---------------------------------------------------------------------------
__global__ __launch_bounds__(256) void scan_partial_kernel(
    const int* __restrict__ counts, int* __restrict__ blockSums) {
    __shared__ int lds[256];
    int base = blockIdx.x * SCAN_CHUNK;
    int t = threadIdx.x;
    int s = 0;
    #pragma unroll
    for (int k = 0; k < 4; ++k) {
        int i = base + t * 4 + k;
        s += (i < N_NODES) ? counts[i] : 0;
    }
    lds[t] = s;
    __syncthreads();
    for (int off = 128; off > 0; off >>= 1) {
        if (t < off) lds[t] += lds[t + off];
        __syncthreads();
    }
    if (t == 0) blockSums[blockIdx.x] = lds[0];
}

__global__ void scan_blocksums_kernel(int* __restrict__ blockSums) {
    if (threadIdx.x == 0) {
        int run = 0;
        for (int i = 0; i < SCAN_BLOCKS; ++i) {
            int c = blockSums[i];
            blockSums[i] = run;
            run += c;
        }
    }
}

__global__ __launch_bounds__(256) void scan_final_kernel(
    const int* __restrict__ counts, const int* __restrict__ blockSums,
    int* __restrict__ offsets) {
    __shared__ int lds[256];
    int base = blockIdx.x * SCAN_CHUNK;
    int t = threadIdx.x;
    int c[4];
    int s = 0;
    #pragma unroll
    for (int k = 0; k < 4; ++k) {
        int i = base + t * 4 + k;
        c[k] = (i < N_NODES) ? counts[i] : 0;
        s += c[k];
    }
    lds[t] = s;
    __syncthreads();
    for (int off = 1; off < 256; off <<= 1) {
        int u = 0;
        if (t >= off) u = lds[t - off];
        __syncthreads();
        if (t >= off) lds[t] += u;
        __syncthreads();
    }
    int texcl = lds[t] - s;
    int run = blockSums[blockIdx.x] + texcl;
    #pragma unroll
    for (int k = 0; k < 4; ++k) {
        int i = base + t * 4 + k;
        if (i < N_NODES) offsets[i] = run;
        run += c[k];
    }
    if (blockIdx.x == 0 && t == 0) offsets[N_NODES] = EDGES_TOTAL;
}

// ---------------------------------------------------------------------------
// bpos[b] = offsets[b*128]  (bucket write cursors for pass A)
// ---------------------------------------------------------------------------
__global__ void bpos_init_kernel(const int* __restrict__ offsets,
                                 int* __restrict__ bpos) {
    int b = blockIdx.x * 256 + threadIdx.x;
    if (b < NB) bpos[b] = offsets[b << B_SHIFT];
}

// ---------------------------------------------------------------------------
// Pass A: LDS-aggregated bucket scatter. (round-0 flush: measured best)
// ---------------------------------------------------------------------------
__global__ __launch_bounds__(256) void bucket_scatter_kernel(
    const int* __restrict__ rows, const int* __restrict__ cols,
    const float* __restrict__ vals, const float* __restrict__ mix,
    int* __restrict__ bpos, int2* __restrict__ tmp) {
    __shared__ int cnt[NB];
    __shared__ int off[NB];
    __shared__ int gbase[NB];
    __shared__ int scanbuf[256];
    __shared__ int2 stage[CHUNK];

    int base = blockIdx.x * CHUNK;
    int t = threadIdx.x;

    for (int i = t; i < NB; i += 256) cnt[i] = 0;
    __syncthreads();

    // Phase 1: count + capture slots
    int myRow[EPT];
    int mySlot[EPT];
    #pragma unroll
    for (int k = 0; k < EPT; ++k) {
        int e = base + k * 256 + t;
        if (e < EDGES_TOTAL) {
            int r = rows[e];
            myRow[k] = r;
            mySlot[k] = atomicAdd(&cnt[r >> B_SHIFT], 1);
        } else {
            myRow[k] = -1;
            mySlot[k] = 0;
        }
    }
    __syncthreads();

    // Exclusive scan of cnt[0..NB) (each thread owns 4 buckets)
    int i0 = t * 4;
    int c4[4];
    int s = 0;
    #pragma unroll
    for (int k = 0; k < 4; ++k) {
        int i = i0 + k;
        c4[k] = (i < NB) ? cnt[i] : 0;
        s += c4[k];
    }
    scanbuf[t] = s;
    __syncthreads();
    for (int o = 1; o < 256; o <<= 1) {
        int u = 0;
        if (t >= o) u = scanbuf[t - o];
        __syncthreads();
        if (t >= o) scanbuf[t] += u;
        __syncthreads();
    }
    int run = scanbuf[t] - s;
    #pragma unroll
    for (int k = 0; k < 4; ++k) {
        int i = i0 + k;
        if (i < NB) off[i] = run;
        run += c4[k];
    }
    // Reserve global ranges (one atomic per bucket per chunk)
    for (int i = t; i < NB; i += 256)
        gbase[i] = atomicAdd(&bpos[i], cnt[i]);
    __syncthreads();

    // Phase 2: place edges into LDS stage, bucket-grouped
    #pragma unroll
    for (int k = 0; k < EPT; ++k) {
        int e = base + k * 256 + t;
        int r = myRow[k];
        if (r >= 0) {
            int b = r >> B_SHIFT;
            int rl = r & (B_ROWS - 1);
            int a = e / NNZ;
            float v = vals[e] * mix[a + 1];
            int packed = (rl << 25) | cols[e];
            stage[off[b] + mySlot[k]] = make_int2(packed, __float_as_int(v));
        }
    }
    __syncthreads();

    // Phase 3: flush contiguous per-bucket runs to global
    for (int i = t; i < NB; i += 256) {
        int c = cnt[i];
        int g = gbase[i];
        int o = off[i];
        for (int j = 0; j < c; ++j) tmp[g + j] = stage[o + j];
    }
}

// ---------------------------------------------------------------------------
// Pass B: one WG per bucket. Reorder the bucket's edges into exact CSR order.
// ---------------------------------------------------------------------------
__global__ __launch_bounds__(256) void bucket_to_csr_kernel(
    const int* __restrict__ offsets, const int2* __restrict__ tmp,
    int2* __restrict__ csr) {
    __shared__ int lpos[B_ROWS];
    int b = blockIdx.x;
    int rbase = b << B_SHIFT;
    int t = threadIdx.x;
    if (t < B_ROWS) {
        int r = rbase + t;
        lpos[t] = offsets[(r < N_NODES) ? r : N_NODES];
    }
    __syncthreads();
    int start = offsets[rbase];
    int endr = rbase + B_ROWS;
    int end = offsets[(endr < N_NODES) ? endr : N_NODES];
    for (int j = start + t; j < end; j += 256) {
        int2 eo = tmp[j];
        int rl = ((unsigned)eo.x) >> 25;
        int col = eo.x & 0x01FFFFFF;
        int p = atomicAdd(&lpos[rl], 1);
        csr[p] = make_int2(col, eo.y);
    }
}

// ---------------------------------------------------------------------------
// Pull (fp16): 16 lanes x uint4(=8 halves) per destination row. fp32 acc.
// At the confirmed ~3.7 TB/s random-granule ceiling; byte-minimal.
// ---------------------------------------------------------------------------
__device__ __forceinline__ void h8_fma(uint4 u, float v, float* a) {
    __half2* hp = reinterpret_cast<__half2*>(&u);
    #pragma unroll
    for (int k = 0; k < 4; ++k) {
        float2 f = __half22float2(hp[k]);
        a[2 * k]     += v * f.x;
        a[2 * k + 1] += v * f.y;
    }
}

__global__ __launch_bounds__(256) void pull16_kernel(
    const int* __restrict__ offsets, const int2* __restrict__ csr,
    const uint4* __restrict__ in16, float4* __restrict__ rep4,
    const float* __restrict__ mix) {
    int row = blockIdx.x * 16 + (threadIdx.x >> 4);
    int l = threadIdx.x & 15;
    if (row >= N_NODES) return;
    int j = offsets[row];
    int end = offsets[row + 1];
    float m0 = mix[0];
    float a[8];
    {
        uint4 xs = in16[(row << 4) | l];
        __half2* hp = reinterpret_cast<__half2*>(&xs);
        #pragma unroll
        for (int k = 0; k < 4; ++k) {
            float2 f = __half22float2(hp[k]);
            a[2 * k]     = m0 * f.x;
            a[2 * k + 1] = m0 * f.y;
        }
    }
    for (; j + 4 <= end; j += 4) {
        int2 e0 = csr[j + 0];
        int2 e1 = csr[j + 1];
        int2 e2 = csr[j + 2];
        int2 e3 = csr[j + 3];
        uint4 y0 = in16[(e0.x << 4) | l];
        uint4 y1 = in16[(e1.x << 4) | l];
        uint4 y2 = in16[(e2.x << 4) | l];
        uint4 y3 = in16[(e3.x << 4) | l];
        h8_fma(y0, __int_as_float(e0.y), a);
        h8_fma(y1, __int_as_float(e1.y), a);
        h8_fma(y2, __int_as_float(e2.y), a);
        h8_fma(y3, __int_as_float(e3.y), a);
    }
    for (; j < end; ++j) {
        int2 e = csr[j];
        uint4 y = in16[(e.x << 4) | l];
        h8_fma(y, __int_as_float(e.y), a);
    }
    int o = (row << 5) | (l << 1);
    rep4[o]     = make_float4(a[0], a[1], a[2], a[3]);
    rep4[o + 1] = make_float4(a[4], a[5], a[6], a[7]);
}

// ---------------------------------------------------------------------------
// Pull (f32, middle path when ws can't hold input16)
// ---------------------------------------------------------------------------
__global__ __launch_bounds__(256) void pull_kernel(
    const int* __restrict__ offsets, const int2* __restrict__ csr,
    const float4* __restrict__ in4, float4* __restrict__ rep4,
    const float* __restrict__ mix) {
    int row = blockIdx.x * 8 + (threadIdx.x >> 5);
    int l = threadIdx.x & 31;
    if (row >= N_NODES) return;
    int j = offsets[row];
    int end = offsets[row + 1];
    float m0 = mix[0];
    float4 x = in4[(row << 5) | l];
    float4 acc = make_float4(m0 * x.x, m0 * x.y, m0 * x.z, m0 * x.w);
    for (; j + 1 < end; j += 2) {
        int2 e0 = csr[j];
        int2 e1 = csr[j + 1];
        float v0 = __int_as_float(e0.y);
        float v1 = __int_as_float(e1.y);
        float4 y0 = in4[(e0.x << 5) | l];
        float4 y1 = in4[(e1.x << 5) | l];
        acc.x += v0 * y0.x; acc.y += v0 * y0.y; acc.z += v0 * y0.z; acc.w += v0 * y0.w;
        acc.x += v1 * y1.x; acc.y += v1 * y1.y; acc.z += v1 * y1.z; acc.w += v1 * y1.w;
    }
    if (j < end) {
        int2 e0 = csr[j];
        float v0 = __int_as_float(e0.y);
        float4 y0 = in4[(e0.x << 5) | l];
        acc.x += v0 * y0.x; acc.y += v0 * y0.y; acc.z += v0 * y0.z; acc.w += v0 * y0.w;
    }
    rep4[(row << 5) | l] = acc;
}

// ---------------------------------------------------------------------------
// Fallback path (small ws): rep = mix[0]*input, then atomic push-scatter
// ---------------------------------------------------------------------------
__global__ __launch_bounds__(256) void rep_init_kernel(
    const float4* __restrict__ in4, float4* __restrict__ rep4,
    const float* __restrict__ mix) {
    int i = blockIdx.x * blockDim.x + threadIdx.x;
    if (i >= N_NODES * D / 4) return;
    float m0 = mix[0];
    float4 v = in4[i];
    v.x *= m0; v.y *= m0; v.z *= m0; v.w *= m0;
    rep4[i] = v;
}

__global__ __launch_bounds__(256) void scatter_kernel(
    const int* __restrict__ rows, const int* __restrict__ cols,
    const float* __restrict__ vals, const float4* __restrict__ in4,
    float* __restrict__ rep, const float* __restrict__ mix) {
    long long gid = (long long)blockIdx.x * blockDim.x + threadIdx.x;
    int e = (int)(gid >> 5);
    int l = (int)(gid & 31);
    if (e >= EDGES_TOTAL) return;
    int a = e / NNZ;
    int row = rows[e];
    int col = cols[e];
    float v = vals[e] * mix[a + 1];
    float4 x = in4[col * 32 + l];
    float* dst = rep + (long long)row * D + l * 4;
    atomicAdd(dst + 0, v * x.x);
    atomicAdd(dst + 1, v * x.y);
    atomicAdd(dst + 2, v * x.z);
    atomicAdd(dst + 3, v * x.w);
}

// ---------------------------------------------------------------------------
// out = rep @ W + bias. v2: register-blocked, 4 rows per thread.
// Theory: v1 read 64B of W from LDS per lane per k4 serving ONE row ->
// 6.4GB LDS ~93us at the 69TB/s LDS ceiling (VALU floor is only 21us).
// v2 reuses each W read across 4 rows -> 1.6GB LDS (~25us). rep loads
// remain once-per-row (32-lane uniform broadcast). 100000 = 3125*32 exactly,
// so no row guards. FMA order per output unchanged -> bitwise-identical out.
// ---------------------------------------------------------------------------
__global__ __launch_bounds__(256) void gemm_kernel(
    const float4* __restrict__ rep4, const float4* __restrict__ w4,
    const float4* __restrict__ bias4, float4* __restrict__ out4) {
    __shared__ float4 Wlds[D * (D / 4)];

    for (int idx = threadIdx.x; idx < D * (D / 4); idx += 256)
        Wlds[idx] = w4[idx];
    __syncthreads();

    int tc = threadIdx.x & 31;
    int rg = threadIdx.x >> 5;          // 0..7, row-group of 4

    for (int base = blockIdx.x * 32; base < N_NODES; base += gridDim.x * 32) {
        int row0 = base + rg * 4;       // rows row0..row0+3, always < N_NODES
        const float4* r0 = rep4 + (size_t)row0 * (D / 4);
        float4 acc0 = make_float4(0.f, 0.f, 0.f, 0.f);
        float4 acc1 = make_float4(0.f, 0.f, 0.f, 0.f);
        float4 acc2 = make_float4(0.f, 0.f, 0.f, 0.f);
        float4 acc3 = make_float4(0.f, 0.f, 0.f, 0.f);
        #pragma unroll 2
        for (int k4 = 0; k4 < D / 4; ++k4) {
            float4 a0 = r0[k4];
            float4 a1 = r0[(D / 4) + k4];
            float4 a2 = r0[2 * (D / 4) + k4];
            float4 a3 = r0[3 * (D / 4) + k4];
            float4 w0 = Wlds[(k4 * 4 + 0) * 32 + tc];
            float4 w1 = Wlds[(k4 * 4 + 1) * 32 + tc];
            float4 w2 = Wlds[(k4 * 4 + 2) * 32 + tc];
            float4 w3 = Wlds[(k4 * 4 + 3) * 32 + tc];
            acc0.x += a0.x * w0.x; acc0.y += a0.x * w0.y; acc0.z += a0.x * w0.z; acc0.w += a0.x * w0.w;
            acc0.x += a0.y * w1.x; acc0.y += a0.y * w1.y; acc0.z += a0.y * w1.z; acc0.w += a0.y * w1.w;
            acc0.x += a0.z * w2.x; acc0.y += a0.z * w2.y; acc0.z += a0.z * w2.z; acc0.w += a0.z * w2.w;
            acc0.x += a0.w * w3.x; acc0.y += a0.w * w3.y; acc0.z += a0.w * w3.z; acc0.w += a0.w * w3.w;
            acc1.x += a1.x * w0.x; acc1.y += a1.x * w0.y; acc1.z += a1.x * w0.z; acc1.w += a1.x * w0.w;
            acc1.x += a1.y * w1.x; acc1.y += a1.y * w1.y; acc1.z += a1.y * w1.z; acc1.w += a1.y * w1.w;
            acc1.x += a1.z * w2.x; acc1.y += a1.z * w2.y; acc1.z += a1.z * w2.z; acc1.w += a1.z * w2.w;
            acc1.x += a1.w * w3.x; acc1.y += a1.w * w3.y; acc1.z += a1.w * w3.z; acc1.w += a1.w * w3.w;
            acc2.x += a2.x * w0.x; acc2.y += a2.x * w0.y; acc2.z += a2.x * w0.z; acc2.w += a2.x * w0.w;
            acc2.x += a2.y * w1.x; acc2.y += a2.y * w1.y; acc2.z += a2.y * w1.z; acc2.w += a2.y * w1.w;
            acc2.x += a2.z * w2.x; acc2.y += a2.z * w2.y; acc2.z += a2.z * w2.z; acc2.w += a2.z * w2.w;
            acc2.x += a2.w * w3.x; acc2.y += a2.w * w3.y; acc2.z += a2.w * w3.z; acc2.w += a2.w * w3.w;
            acc3.x += a3.x * w0.x; acc3.y += a3.x * w0.y; acc3.z += a3.x * w0.z; acc3.w += a3.x * w0.w;
            acc3.x += a3.y * w1.x; acc3.y += a3.y * w1.y; acc3.z += a3.y * w1.z; acc3.w += a3.y * w1.w;
            acc3.x += a3.z * w2.x; acc3.y += a3.z * w2.y; acc3.z += a3.z * w2.z; acc3.w += a3.z * w2.w;
            acc3.x += a3.w * w3.x; acc3.y += a3.w * w3.y; acc3.z += a3.w * w3.z; acc3.w += a3.w * w3.w;
        }
        float4 b = bias4[tc];
        acc0.x += b.x; acc0.y += b.y; acc0.z += b.z; acc0.w += b.w;
        acc1.x += b.x; acc1.y += b.y; acc1.z += b.z; acc1.w += b.w;
        acc2.x += b.x; acc2.y += b.y; acc2.z += b.z; acc2.w += b.w;
        acc3.x += b.x; acc3.y += b.y; acc3.z += b.z; acc3.w += b.w;
        out4[(size_t)(row0 + 0) * (D / 4) + tc] = acc0;
        out4[(size_t)(row0 + 1) * (D / 4) + tc] = acc1;
        out4[(size_t)(row0 + 2) * (D / 4) + tc] = acc2;
        out4[(size_t)(row0 + 3) * (D / 4) + tc] = acc3;
    }
}

// ---------------------------------------------------------------------------
extern "C" void kernel_launch(void* const* d_in, const int* in_sizes, int n_in,
                              void* d_out, int out_size, void* d_ws, size_t ws_size,
                              hipStream_t stream) {
    const float* input         = (const float*)d_in[0];
    const int*   adj_rows      = (const int*)d_in[1];
    const int*   adj_cols      = (const int*)d_in[2];
    const float* adj_vals      = (const float*)d_in[3];
    const float* weight        = (const float*)d_in[4];
    const float* linear_weight = (const float*)d_in[5];
    const float* bias          = (const float*)d_in[6];

    float* out = (float*)d_out;                    // [N_NODES, D]
    float* rep = out + (size_t)N_NODES * D;        // [N_NODES, D]

    // tmp (bucketed edges) aliases the `out` region: out is only written by
    // the final gemm, after tmp's lifetime (passA write -> passB read) ends.
    int2* tmp = (int2*)out;                        // 28.8MB <= 51.2MB

    // workspace layout
    char* ws = (char*)d_ws;
    float* mix      = (float*)ws;                        ws += 32;
    int*   counts   = (int*)ws;                          ws += sizeof(int) * N_NODES;
    int*   offsets  = (int*)ws;                          ws += sizeof(int) * (N_NODES + 4);
    int*   blockSums= (int*)ws;                          ws += sizeof(int) * 128;
    int*   bpos     = (int*)ws;                          ws += sizeof(int) * (NB + 2);
    ws = (char*)(((uintptr_t)ws + 15) & ~(uintptr_t)15);
    int2*  csr      = (int2*)ws;                         ws += sizeof(int2) * EDGES_TOTAL;
    size_t needed1 = (size_t)(ws - (char*)d_ws);
    ws = (char*)(((uintptr_t)ws + 15) & ~(uintptr_t)15);
    uint4* input16  = (uint4*)ws;                        ws += sizeof(unsigned short) * (size_t)N_NODES * D;
    size_t needed2 = (size_t)(ws - (char*)d_ws);

    softmax_mix_kernel<<<1, 64, 0, stream>>>(linear_weight, mix);

    if (ws_size >= needed1) {
        bool fp16path = (ws_size >= needed2);

        hipMemsetAsync(counts, 0, sizeof(int) * N_NODES, stream);
        if (fp16path) {
            int total = N_NODES * D / 8;
            conv16_kernel<<<(total + 255) / 256, 256, 0, stream>>>(
                (const float4*)input, input16);
        }
        {
            int blocks = (EDGES_TOTAL + 255) / 256;
            hist_kernel<<<blocks, 256, 0, stream>>>(adj_rows, counts);
        }
        scan_partial_kernel<<<SCAN_BLOCKS, 256, 0, stream>>>(counts, blockSums);
        scan_blocksums_kernel<<<1, 64, 0, stream>>>(blockSums);
        scan_final_kernel<<<SCAN_BLOCKS, 256, 0, stream>>>(counts, blockSums, offsets);
        bpos_init_kernel<<<(NB + 255) / 256, 256, 0, stream>>>(offsets, bpos);
        {
            int blocks = (EDGES_TOTAL + CHUNK - 1) / CHUNK;
            bucket_scatter_kernel<<<blocks, 256, 0, stream>>>(
                adj_rows, adj_cols, adj_vals, mix, bpos, tmp);
        }
        bucket_to_csr_kernel<<<NB, 256, 0, stream>>>(offsets, tmp, csr);
        if (fp16path) {
            int blocks = (N_NODES * 16 + 255) / 256;
            pull16_kernel<<<blocks, 256, 0, stream>>>(
                offsets, csr, input16, (float4*)rep, mix);
        } else {
            long long threads = (long long)N_NODES * 32;
            int blocks = (int)((threads + 255) / 256);
            pull_kernel<<<blocks, 256, 0, stream>>>(
                offsets, csr, (const float4*)input, (float4*)rep, mix);
        }
    } else {
        {
            int total = N_NODES * D / 4;
            int blocks = (total + 255) / 256;
            rep_init_kernel<<<blocks, 256, 0, stream>>>(
                (const float4*)input, (float4*)rep, mix);
        }
        {
            long long threads = (long long)EDGES_TOTAL * 32;
            int blocks = (int)((threads + 255) / 256);
            scatter_kernel<<<blocks, 256, 0, stream>>>(
                adj_rows, adj_cols, adj_vals, (const float4*)input, rep, mix);
        }
    }

    gemm_kernel<<<2048, 256, 0, stream>>>(
        (const float4*)rep, (const float4*)weight,
        (const float4*)bias, (float4*)out);
}